// Round 1
// baseline (14439.174 us; speedup 1.0000x reference)
//
#include <hip/hip_runtime.h>

// GraphSAGE 3-layer, fp32. N=100000 nodes, E=1600000 edges.
// Layer l: h_{l+1} = act( h_l @ Ws.T + (scatter_mean(h_l, edges)) @ Wn.T + b )
// Strategy this round:
//   - degree/rdeg computed once (atomicAdd counts, then 1/max(deg,1))
//   - aggregation: atomicAdd scatter of raw sums into `agg`; rdeg folded into GEMM A-load
//   - fused GEMM over K' = 2K: A' = [h | rdeg*agg], B' = [Wself ; Wneigh]
//   - layer-1 GEMM in place (block covers full row width; reads precede writes)

constexpr int NN = 100000;
constexpr int NE = 1600000;

__global__ void deg_kernel(const int* __restrict__ dst, float* __restrict__ deg, int n) {
    int e = blockIdx.x * blockDim.x + threadIdx.x;
    if (e < n) atomicAdd(&deg[dst[e]], 1.0f);
}

__global__ void rdeg_kernel(float* deg, int n) {
    int i = blockIdx.x * blockDim.x + threadIdx.x;
    if (i < n) deg[i] = 1.0f / fmaxf(deg[i], 1.0f);
}

template<int D>
__global__ void scatter_add_kernel(const float* __restrict__ h, const int* __restrict__ src,
                                   const int* __restrict__ dst, float* agg, int n) {
    constexpr int TPE = D / 4;          // threads per edge (float4 each)
    constexpr int EPB = 256 / TPE;      // edges per block
    const int lane = threadIdx.x % TPE;
    const int es   = threadIdx.x / TPE;
    const int e = blockIdx.x * EPB + es;
    if (e >= n) return;
    const int s = src[e], d = dst[e];
    const float4 v = reinterpret_cast<const float4*>(h + (size_t)s * D)[lane];
    float* o = agg + (size_t)d * D + lane * 4;
    atomicAdd(o + 0, v.x);
    atomicAdd(o + 1, v.y);
    atomicAdd(o + 2, v.z);
    atomicAdd(o + 3, v.w);
}

// out[m][f] = sum_k h[m][k]*Wself[f][k] + rdeg[m]*sum_k agg[m][k]*Wneigh[f][k] + b[f]
// BF == F: one block covers the full output row width -> in-place (out==h) is safe.
template<int K, int F, int BM, int NTX, int NTY, bool RELU, bool GUARD>
__global__ __launch_bounds__(256, 2) void sage_gemm(
    const float* h, const float* agg,
    const float* __restrict__ rdeg,
    const float* __restrict__ Wself, const float* __restrict__ Wneigh,
    const float* __restrict__ bias, float* out) {

    constexpr int BK = 32;
    constexpr int BF = F;
    constexpr int TM = BM / NTY;
    constexpr int TF = BF / NTX;
    constexpr int KA = 2 * K;
    constexpr int A_ITER = (BM * BK / 4) / 256;
    constexpr int B_ITER = (BF * BK / 4) / 256;

    __shared__ float As[BK][BM + 1];
    __shared__ float Bs[BK][BF + 1];

    const int tid = threadIdx.x;
    const int bm = blockIdx.x * BM;
    const int tx = tid % NTX, ty = tid / NTX;

    float acc[TM][TF];
#pragma unroll
    for (int i = 0; i < TM; ++i)
#pragma unroll
        for (int j = 0; j < TF; ++j) acc[i][j] = 0.f;

    for (int k0 = 0; k0 < KA; k0 += BK) {
        const bool isH = (k0 < K);
        const float* Aptr = isH ? h : agg;
        const float* Bptr = isH ? Wself : Wneigh;
        const int kk0 = isH ? k0 : (k0 - K);

#pragma unroll
        for (int it = 0; it < A_ITER; ++it) {
            const int s = tid + it * 256;
            const int m = s / (BK / 4);
            const int kq = s % (BK / 4);
            float4 v = make_float4(0.f, 0.f, 0.f, 0.f);
            const int mg = bm + m;
            if (!GUARD || mg < NN) {
                v = *reinterpret_cast<const float4*>(Aptr + (size_t)mg * K + kk0 + kq * 4);
                if (!isH) {
                    const float r = rdeg[mg];
                    v.x *= r; v.y *= r; v.z *= r; v.w *= r;
                }
            }
            As[kq * 4 + 0][m] = v.x; As[kq * 4 + 1][m] = v.y;
            As[kq * 4 + 2][m] = v.z; As[kq * 4 + 3][m] = v.w;
        }
#pragma unroll
        for (int it = 0; it < B_ITER; ++it) {
            const int s = tid + it * 256;
            const int f = s / (BK / 4);
            const int kq = s % (BK / 4);
            const float4 v = *reinterpret_cast<const float4*>(Bptr + (size_t)f * K + kk0 + kq * 4);
            Bs[kq * 4 + 0][f] = v.x; Bs[kq * 4 + 1][f] = v.y;
            Bs[kq * 4 + 2][f] = v.z; Bs[kq * 4 + 3][f] = v.w;
        }
        __syncthreads();

#pragma unroll
        for (int kk = 0; kk < BK; ++kk) {
            float a[TM], b[TF];
#pragma unroll
            for (int i = 0; i < TM; ++i) a[i] = As[kk][ty + NTY * i];
#pragma unroll
            for (int j = 0; j < TF; ++j) b[j] = Bs[kk][tx + NTX * j];
#pragma unroll
            for (int i = 0; i < TM; ++i)
#pragma unroll
                for (int j = 0; j < TF; ++j)
                    acc[i][j] += a[i] * b[j];
        }
        __syncthreads();
    }

#pragma unroll
    for (int i = 0; i < TM; ++i) {
        const int m = bm + ty + NTY * i;
        if (GUARD && m >= NN) continue;
#pragma unroll
        for (int j = 0; j < TF; ++j) {
            const int f = tx + NTX * j;
            float v = acc[i][j] + bias[f];
            if (RELU) v = fmaxf(v, 0.f);
            out[(size_t)m * F + f] = v;
        }
    }
}

extern "C" void kernel_launch(void* const* d_in, const int* in_sizes, int n_in,
                              void* d_out, int out_size, void* d_ws, size_t ws_size,
                              hipStream_t stream) {
    const float* feats = (const float*)d_in[0];
    const int*   esrc  = (const int*)d_in[1];
    const int*   edst  = (const int*)d_in[2];
    const float* W0s = (const float*)d_in[3];
    const float* W0n = (const float*)d_in[4];
    const float* b0  = (const float*)d_in[5];
    const float* W1s = (const float*)d_in[6];
    const float* W1n = (const float*)d_in[7];
    const float* b1  = (const float*)d_in[8];
    const float* W2s = (const float*)d_in[9];
    const float* W2n = (const float*)d_in[10];
    const float* b2  = (const float*)d_in[11];
    float* out = (float*)d_out;

    char* ws = (char*)d_ws;
    float* rdeg = (float*)ws;                                     // N floats
    float* agg  = (float*)(ws + (1 << 20));                       // N*256 floats
    float* h    = (float*)(ws + (1 << 20) + (size_t)NN * 256 * 4); // N*256 floats

    // degrees (same every layer)
    hipMemsetAsync(rdeg, 0, NN * sizeof(float), stream);
    deg_kernel<<<(NE + 255) / 256, 256, 0, stream>>>(edst, rdeg, NE);
    rdeg_kernel<<<(NN + 255) / 256, 256, 0, stream>>>(rdeg, NN);

    // ---- layer 0: feats[N,128] -> h[N,256], ReLU
    hipMemsetAsync(agg, 0, (size_t)NN * 128 * sizeof(float), stream);
    scatter_add_kernel<128><<<(NE + 7) / 8, 256, 0, stream>>>(feats, esrc, edst, agg, NE);
    sage_gemm<128, 256, 64, 32, 8, true, true>
        <<<dim3((NN + 63) / 64), 256, 0, stream>>>(feats, agg, rdeg, W0s, W0n, b0, h);

    // ---- layer 1: h[N,256] -> h[N,256] (in place), ReLU
    hipMemsetAsync(agg, 0, (size_t)NN * 256 * sizeof(float), stream);
    scatter_add_kernel<256><<<(NE + 3) / 4, 256, 0, stream>>>(h, esrc, edst, agg, NE);
    sage_gemm<256, 256, 64, 32, 8, true, true>
        <<<dim3((NN + 63) / 64), 256, 0, stream>>>(h, agg, rdeg, W1s, W1n, b1, h);

    // ---- layer 2: h[N,256] -> out[N,64], no act
    hipMemsetAsync(agg, 0, (size_t)NN * 256 * sizeof(float), stream);
    scatter_add_kernel<256><<<(NE + 3) / 4, 256, 0, stream>>>(h, esrc, edst, agg, NE);
    sage_gemm<256, 64, 128, 16, 16, false, true>
        <<<dim3((NN + 127) / 128), 256, 0, stream>>>(h, agg, rdeg, W2s, W2n, b2, out);
}

// Round 2
// 1854.092 us; speedup vs baseline: 7.7877x; 7.7877x over previous
//
#include <hip/hip_runtime.h>

// GraphSAGE 3-layer, fp32. N=100000 nodes, E=1600000 edges.
// Round 2: atomic scatter -> CSR gather.
//   - CSR build per call: int-histogram degrees, single-block prefix scan,
//     atomic bucket fill (int atomics only, ~1.6M each: cheap).
//   - gather_mean: one wave per dst node, lanes cover the row (float4),
//     4-edge unroll for memory-level parallelism. Writes agg exactly once.
//   - rdeg folded into gather output (agg holds the MEAN already).
//   - layer 2 transform-before-aggregate: z = h@W2n.T (N,64, no bias) THEN
//     aggregate 64-wide (4x less gather traffic); final GEMM adds b2 + aggz.
//   - layer-1 GEMM in place (block covers full row width).

constexpr int NN = 100000;
constexpr int NE = 1600000;

__global__ void deg_hist_kernel(const int* __restrict__ dst, int* __restrict__ degi, int n) {
    int e = blockIdx.x * blockDim.x + threadIdx.x;
    if (e < n) atomicAdd(&degi[dst[e]], 1);
}

// single block, 256 threads: exclusive prefix sum over degi -> row_start & cursor, plus rdeg
__global__ void scan_kernel(const int* __restrict__ degi, int* __restrict__ row_start,
                            int* __restrict__ cursor, float* __restrict__ rdeg) {
    __shared__ int psum[257];
    const int t = threadIdx.x;
    constexpr int CH = (NN + 255) / 256;
    const int b = t * CH;
    const int e = min(b + CH, NN);
    int s = 0;
    for (int i = b; i < e; ++i) s += degi[i];
    psum[t + 1] = s;
    __syncthreads();
    if (t == 0) {
        psum[0] = 0;
        for (int i = 1; i <= 256; ++i) psum[i] += psum[i - 1];
        row_start[NN] = NE;
    }
    __syncthreads();
    int run = psum[t];
    for (int i = b; i < e; ++i) {
        const int d = degi[i];
        row_start[i] = run;
        cursor[i] = run;
        rdeg[i] = 1.0f / (float)max(d, 1);
        run += d;
    }
}

__global__ void fill_csr_kernel(const int* __restrict__ src, const int* __restrict__ dst,
                                int* __restrict__ cursor, int* __restrict__ csr, int n) {
    int e = blockIdx.x * blockDim.x + threadIdx.x;
    if (e < n) {
        const int p = atomicAdd(&cursor[dst[e]], 1);
        csr[p] = src[e];
    }
}

// One wave per node. D floats/row, VPL = D/64 floats per lane.
template<int D>
__global__ __launch_bounds__(256) void gather_mean_kernel(
    const float* __restrict__ rows, const int* __restrict__ row_start,
    const int* __restrict__ csr, const float* __restrict__ rdeg,
    float* __restrict__ out) {
    constexpr int VPL = D / 64;
    const int node = (int)((blockIdx.x * (unsigned)blockDim.x + threadIdx.x) >> 6);
    if (node >= NN) return;
    const int lane = threadIdx.x & 63;
    const int beg = row_start[node];
    const int end = row_start[node + 1];
    float acc[VPL];
#pragma unroll
    for (int u = 0; u < VPL; ++u) acc[u] = 0.f;

    int e = beg;
    for (; e + 4 <= end; e += 4) {
        const int sv[4] = {csr[e + 0], csr[e + 1], csr[e + 2], csr[e + 3]};
#pragma unroll
        for (int u = 0; u < 4; ++u) {
            const float* p = rows + (size_t)sv[u] * D + lane * VPL;
            if constexpr (VPL == 4) {
                const float4 v = *reinterpret_cast<const float4*>(p);
                acc[0] += v.x; acc[1] += v.y; acc[2] += v.z; acc[3] += v.w;
            } else if constexpr (VPL == 2) {
                const float2 v = *reinterpret_cast<const float2*>(p);
                acc[0] += v.x; acc[1] += v.y;
            } else {
                acc[0] += *p;
            }
        }
    }
    for (; e < end; ++e) {
        const float* p = rows + (size_t)csr[e] * D + lane * VPL;
        if constexpr (VPL == 4) {
            const float4 v = *reinterpret_cast<const float4*>(p);
            acc[0] += v.x; acc[1] += v.y; acc[2] += v.z; acc[3] += v.w;
        } else if constexpr (VPL == 2) {
            const float2 v = *reinterpret_cast<const float2*>(p);
            acc[0] += v.x; acc[1] += v.y;
        } else {
            acc[0] += *p;
        }
    }
    const float r = rdeg[node];
    float* o = out + (size_t)node * D + lane * VPL;
    if constexpr (VPL == 4) {
        *reinterpret_cast<float4*>(o) = make_float4(acc[0] * r, acc[1] * r, acc[2] * r, acc[3] * r);
    } else if constexpr (VPL == 2) {
        *reinterpret_cast<float2*>(o) = make_float2(acc[0] * r, acc[1] * r);
    } else {
        *o = acc[0] * r;
    }
}

// out[m][f] = sum_k A1[m][k]*W1[f][k] (+ sum_k A2[m][k]*W2[f][k]) + bias[f] (+ addC[m][f]); opt ReLU
// BF == F: one block covers the full output row width -> in-place (out==A1) is safe.
// NOTE: A1/A2/out intentionally NOT __restrict__ (layer 1 runs in place).
template<int K1, int K2, int F, int BM, int NTX, int NTY, bool RELU, bool HASADD, bool HASBIAS>
__global__ __launch_bounds__(256, 2) void sage_gemm(
    const float* A1, const float* A2,
    const float* __restrict__ W1, const float* __restrict__ W2,
    const float* __restrict__ bias, const float* __restrict__ addC,
    float* out) {

    constexpr int BK = 32;
    constexpr int BF = F;
    constexpr int TM = BM / NTY;
    constexpr int TF = BF / NTX;
    constexpr int KA = K1 + K2;
    constexpr int A_ITER = (BM * BK / 4) / 256;
    constexpr int B_ITER = (BF * BK / 4) / 256;

    __shared__ float As[BK][BM + 1];
    __shared__ float Bs[BK][BF + 1];

    const int tid = threadIdx.x;
    const int bm = blockIdx.x * BM;
    const int tx = tid % NTX, ty = tid / NTX;

    float acc[TM][TF];
#pragma unroll
    for (int i = 0; i < TM; ++i)
#pragma unroll
        for (int j = 0; j < TF; ++j) acc[i][j] = 0.f;

    for (int k0 = 0; k0 < KA; k0 += BK) {
        const bool isH = (k0 < K1);
        const float* Aptr = isH ? A1 : A2;
        const float* Bptr = isH ? W1 : W2;
        const int kk0 = isH ? k0 : (k0 - K1);
        const int stride = isH ? K1 : K2;

#pragma unroll
        for (int it = 0; it < A_ITER; ++it) {
            const int s = tid + it * 256;
            const int m = s / (BK / 4);
            const int kq = s % (BK / 4);
            float4 v = make_float4(0.f, 0.f, 0.f, 0.f);
            const int mg = bm + m;
            if (mg < NN)
                v = *reinterpret_cast<const float4*>(Aptr + (size_t)mg * stride + kk0 + kq * 4);
            As[kq * 4 + 0][m] = v.x; As[kq * 4 + 1][m] = v.y;
            As[kq * 4 + 2][m] = v.z; As[kq * 4 + 3][m] = v.w;
        }
#pragma unroll
        for (int it = 0; it < B_ITER; ++it) {
            const int s = tid + it * 256;
            const int f = s / (BK / 4);
            const int kq = s % (BK / 4);
            const float4 v = *reinterpret_cast<const float4*>(Bptr + (size_t)f * stride + kk0 + kq * 4);
            Bs[kq * 4 + 0][f] = v.x; Bs[kq * 4 + 1][f] = v.y;
            Bs[kq * 4 + 2][f] = v.z; Bs[kq * 4 + 3][f] = v.w;
        }
        __syncthreads();

#pragma unroll
        for (int kk = 0; kk < BK; ++kk) {
            float a[TM], b[TF];
#pragma unroll
            for (int i = 0; i < TM; ++i) a[i] = As[kk][ty + NTY * i];
#pragma unroll
            for (int j = 0; j < TF; ++j) b[j] = Bs[kk][tx + NTX * j];
#pragma unroll
            for (int i = 0; i < TM; ++i)
#pragma unroll
                for (int j = 0; j < TF; ++j)
                    acc[i][j] += a[i] * b[j];
        }
        __syncthreads();
    }

#pragma unroll
    for (int i = 0; i < TM; ++i) {
        const int m = bm + ty + NTY * i;
        if (m >= NN) continue;
#pragma unroll
        for (int j = 0; j < TF; ++j) {
            const int f = tx + NTX * j;
            float v = acc[i][j];
            if (HASBIAS) v += bias[f];
            if (HASADD) v += addC[(size_t)m * F + f];
            if (RELU) v = fmaxf(v, 0.f);
            out[(size_t)m * F + f] = v;
        }
    }
}

extern "C" void kernel_launch(void* const* d_in, const int* in_sizes, int n_in,
                              void* d_out, int out_size, void* d_ws, size_t ws_size,
                              hipStream_t stream) {
    const float* feats = (const float*)d_in[0];
    const int*   esrc  = (const int*)d_in[1];
    const int*   edst  = (const int*)d_in[2];
    const float* W0s = (const float*)d_in[3];
    const float* W0n = (const float*)d_in[4];
    const float* b0  = (const float*)d_in[5];
    const float* W1s = (const float*)d_in[6];
    const float* W1n = (const float*)d_in[7];
    const float* b1  = (const float*)d_in[8];
    const float* W2s = (const float*)d_in[9];
    const float* W2n = (const float*)d_in[10];
    const float* b2  = (const float*)d_in[11];
    float* out = (float*)d_out;

    char* p = (char*)d_ws;
    auto alloc = [&](size_t bytes) { char* r = p; p += (bytes + 255) & ~255ull; return r; };
    int*   degi      = (int*)alloc((size_t)NN * 4);
    int*   row_start = (int*)alloc(((size_t)NN + 1) * 4);
    int*   cursor    = (int*)alloc((size_t)NN * 4);
    int*   csr       = (int*)alloc((size_t)NE * 4);
    float* rdeg      = (float*)alloc((size_t)NN * 4);
    float* agg       = (float*)alloc((size_t)NN * 256 * 4);
    float* h         = (float*)alloc((size_t)NN * 256 * 4);
    float* z    = agg;                   // layer-2: z (N,64) in first half of agg
    float* aggz = agg + (size_t)NN * 64; // layer-2: aggregated z (N,64)

    // ---- CSR build (per call; ws is re-poisoned between launches)
    hipMemsetAsync(degi, 0, (size_t)NN * 4, stream);
    deg_hist_kernel<<<(NE + 255) / 256, 256, 0, stream>>>(edst, degi, NE);
    scan_kernel<<<1, 256, 0, stream>>>(degi, row_start, cursor, rdeg);
    fill_csr_kernel<<<(NE + 255) / 256, 256, 0, stream>>>(esrc, edst, cursor, csr, NE);

    const int gather_grid = (NN + 3) / 4;   // 4 waves/block, 1 wave/node

    // ---- layer 0: feats[N,128] -> h[N,256], ReLU
    gather_mean_kernel<128><<<gather_grid, 256, 0, stream>>>(feats, row_start, csr, rdeg, agg);
    sage_gemm<128, 128, 256, 64, 32, 8, true, false, true>
        <<<dim3((NN + 63) / 64), 256, 0, stream>>>(feats, agg, W0s, W0n, b0, nullptr, h);

    // ---- layer 1: h[N,256] -> h[N,256] (in place), ReLU
    gather_mean_kernel<256><<<gather_grid, 256, 0, stream>>>(h, row_start, csr, rdeg, agg);
    sage_gemm<256, 256, 256, 64, 32, 8, true, false, true>
        <<<dim3((NN + 63) / 64), 256, 0, stream>>>(h, agg, W1s, W1n, b1, nullptr, h);

    // ---- layer 2: transform-before-aggregate
    // z = h @ W2n.T  (N,64), NO bias (b2 added exactly once in the final GEMM)
    sage_gemm<256, 0, 64, 128, 16, 16, false, false, false>
        <<<dim3((NN + 127) / 128), 256, 0, stream>>>(h, nullptr, W2n, nullptr, nullptr, nullptr, z);
    gather_mean_kernel<64><<<gather_grid, 256, 0, stream>>>(z, row_start, csr, rdeg, aggz);
    // out = h @ W2s.T + b2 + aggz
    sage_gemm<256, 0, 64, 128, 16, 16, false, true, true>
        <<<dim3((NN + 127) / 128), 256, 0, stream>>>(h, nullptr, W2s, nullptr, b2, aggz, out);
}

// Round 3
// 999.457 us; speedup vs baseline: 14.4470x; 1.8551x over previous
//
#include <hip/hip_runtime.h>

// GraphSAGE 3-layer. Round 3: bf16 MFMA GEMMs + bf16 activations.
//   - CSR gather aggregation (round-2 structure kept)
//   - all GEMMs use v_mfma_f32_16x16x32_bf16, fp32 accum, fused epilogue
//   - LDS tiles [rows][BK=64] bf16 with XOR swizzle (byte ^= (row&7)<<4)
//   - h stored bf16 -> gather traffic halved
//   - layer 2 transform-before-aggregate (64-wide gather)

constexpr int NN = 100000;
constexpr int NE = 1600000;

typedef short s16x8 __attribute__((ext_vector_type(8)));
typedef float f32x4 __attribute__((ext_vector_type(4)));

struct ushort4_t { unsigned short x, y, z, w; };
struct ushort2_t { unsigned short x, y; };

__device__ __forceinline__ float bf2f(unsigned short u) {
    union { unsigned int i; float f; } c; c.i = ((unsigned int)u) << 16; return c.f;
}
__device__ __forceinline__ unsigned short f2bf(float f) {
    union { float f; unsigned int i; } c; c.f = f;
    unsigned int r = (c.i + 0x7fffu + ((c.i >> 16) & 1u)) >> 16;
    return (unsigned short)r;
}

// ---------------- CSR build ----------------
__global__ void deg_hist_kernel(const int* __restrict__ dst, int* __restrict__ degi, int n) {
    int e = blockIdx.x * blockDim.x + threadIdx.x;
    if (e < n) atomicAdd(&degi[dst[e]], 1);
}

__global__ void scan_kernel(const int* __restrict__ degi, int* __restrict__ row_start,
                            int* __restrict__ cursor, float* __restrict__ rdeg) {
    __shared__ int psum[257];
    const int t = threadIdx.x;
    constexpr int CH = (NN + 255) / 256;
    const int b = t * CH;
    const int e = min(b + CH, NN);
    int s = 0;
    for (int i = b; i < e; ++i) s += degi[i];
    psum[t + 1] = s;
    __syncthreads();
    if (t == 0) {
        psum[0] = 0;
        for (int i = 1; i <= 256; ++i) psum[i] += psum[i - 1];
        row_start[NN] = NE;
    }
    __syncthreads();
    int run = psum[t];
    for (int i = b; i < e; ++i) {
        const int d = degi[i];
        row_start[i] = run;
        cursor[i] = run;
        rdeg[i] = 1.0f / (float)max(d, 1);
        run += d;
    }
}

__global__ void fill_csr_kernel(const int* __restrict__ src, const int* __restrict__ dst,
                                int* __restrict__ cursor, int* __restrict__ csr, int n) {
    int e = blockIdx.x * blockDim.x + threadIdx.x;
    if (e < n) {
        const int p = atomicAdd(&cursor[dst[e]], 1);
        csr[p] = src[e];
    }
}

// ---------------- fp32 -> bf16 converts ----------------
__global__ void cvt_f32_bf16(const float* __restrict__ src, unsigned short* __restrict__ dst, int nquad) {
    int i = blockIdx.x * blockDim.x + threadIdx.x;
    if (i >= nquad) return;
    const float4 v = reinterpret_cast<const float4*>(src)[i];
    ushort4_t o = { f2bf(v.x), f2bf(v.y), f2bf(v.z), f2bf(v.w) };
    reinterpret_cast<ushort4_t*>(dst)[i] = o;
}

// all six weight matrices -> one contiguous bf16 buffer
__global__ void cvt_weights(const float* a, const float* b, const float* c,
                            const float* d, const float* e, const float* f,
                            unsigned short* __restrict__ o) {
    int i = blockIdx.x * blockDim.x + threadIdx.x;   // quad index
    int q = i * 4;
    if (q >= 229376) return;
    const float* s; int off;
    if      (q <  32768) { s = a; off = 0; }
    else if (q <  65536) { s = b; off = 32768; }
    else if (q < 131072) { s = c; off = 65536; }
    else if (q < 196608) { s = d; off = 131072; }
    else if (q < 212992) { s = e; off = 196608; }
    else                 { s = f; off = 212992; }
    const float4 v = *reinterpret_cast<const float4*>(s + (q - off));
    ushort4_t ov = { f2bf(v.x), f2bf(v.y), f2bf(v.z), f2bf(v.w) };
    *reinterpret_cast<ushort4_t*>(o + q) = ov;
}

// ---------------- gather-mean (bf16 rows, fp32 accum, bf16 out) ----------------
template<int D>
__global__ __launch_bounds__(256) void gather_mean_bf16(
    const unsigned short* __restrict__ rows, const int* __restrict__ row_start,
    const int* __restrict__ csr, const float* __restrict__ rdeg,
    unsigned short* __restrict__ out) {
    constexpr int VPL = D / 64;
    const int node = (int)((blockIdx.x * (unsigned)blockDim.x + threadIdx.x) >> 6);
    if (node >= NN) return;
    const int lane = threadIdx.x & 63;
    const int beg = row_start[node];
    const int end = row_start[node + 1];
    float acc[VPL];
#pragma unroll
    for (int u = 0; u < VPL; ++u) acc[u] = 0.f;

    auto accum = [&](int s) {
        const unsigned short* p = rows + (size_t)s * D + lane * VPL;
        if constexpr (VPL == 4) {
            const ushort4_t v = *reinterpret_cast<const ushort4_t*>(p);
            acc[0] += bf2f(v.x); acc[1] += bf2f(v.y); acc[2] += bf2f(v.z); acc[3] += bf2f(v.w);
        } else if constexpr (VPL == 2) {
            const ushort2_t v = *reinterpret_cast<const ushort2_t*>(p);
            acc[0] += bf2f(v.x); acc[1] += bf2f(v.y);
        } else {
            acc[0] += bf2f(*p);
        }
    };

    int e = beg;
    for (; e + 4 <= end; e += 4) {
        const int s0 = csr[e], s1 = csr[e + 1], s2 = csr[e + 2], s3 = csr[e + 3];
        accum(s0); accum(s1); accum(s2); accum(s3);
    }
    for (; e < end; ++e) accum(csr[e]);

    const float r = rdeg[node];
    unsigned short* o = out + (size_t)node * D + lane * VPL;
    if constexpr (VPL == 4) {
        ushort4_t v = { f2bf(acc[0] * r), f2bf(acc[1] * r), f2bf(acc[2] * r), f2bf(acc[3] * r) };
        *reinterpret_cast<ushort4_t*>(o) = v;
    } else if constexpr (VPL == 2) {
        ushort2_t v = { f2bf(acc[0] * r), f2bf(acc[1] * r) };
        *reinterpret_cast<ushort2_t*>(o) = v;
    } else {
        *o = f2bf(acc[0] * r);
    }
}

// ---------------- MFMA GEMM ----------------
// out[m][f] = sum_k A[m][k]*W[f][k] (+bias[f]) (+addC[m][f]) ; optional ReLU
// A = [A1 | A2] along K (K1 + K2, both multiples of 64). W likewise [W1 ; W2].
// Tile: BM=128 x BN (128 or 64), BK=64, 256 threads = 4 waves (2x2 wave grid).
// LDS layout: [row][BK] bf16, XOR-swizzled: byte ^= (row&7)<<4.
template<int K1, int K2, int F, int BN, bool RELU, bool HASBIAS, bool HASADD, bool OUTBF16>
__global__ __launch_bounds__(256, 2) void mfma_gemm(
    const unsigned short* A1, const unsigned short* A2,
    const unsigned short* __restrict__ W1, const unsigned short* __restrict__ W2,
    const float* __restrict__ bias, const unsigned short* __restrict__ addC,
    void* outp) {

    constexpr int BM = 128, BK = 64;
    constexpr int KA = K1 + K2;
    constexpr int WN = BN / 2;          // wave col extent (64 or 32)
    constexpr int FM = 4, FN = WN / 16;
    constexpr int ABASE = 0;
    constexpr int BBASE = BM * BK * 2;  // 16384
    constexpr int B_ITERS = (BN * 8) / 256;

    __shared__ __align__(16) char smem[(BM + BN) * BK * 2];

    const int tid = threadIdx.x;
    const int l = tid & 63;
    const int w = tid >> 6;
    const int wr = w >> 1, wc = w & 1;
    const int lr = l & 15, lhi = l >> 4;
    const int bm = blockIdx.x * BM;
    const int bn = blockIdx.y * BN;

    f32x4 acc[FM][FN];
#pragma unroll
    for (int i = 0; i < FM; ++i)
#pragma unroll
        for (int j = 0; j < FN; ++j) acc[i][j] = (f32x4){0.f, 0.f, 0.f, 0.f};

    int rowA[FM], rowB[FN];
#pragma unroll
    for (int fm = 0; fm < FM; ++fm) rowA[fm] = wr * 64 + fm * 16 + lr;
#pragma unroll
    for (int fn = 0; fn < FN; ++fn) rowB[fn] = wc * WN + fn * 16 + lr;

    for (int k0 = 0; k0 < KA; k0 += BK) {
        const bool inR1 = (k0 < K1);
        const unsigned short* Ap = inR1 ? A1 : A2;
        const unsigned short* Wp = inR1 ? W1 : W2;
        const int stride = inR1 ? K1 : K2;
        const int kk0 = inR1 ? k0 : (k0 - K1);

        // stage A tile: 128 x 64 bf16, 16B per thread-iter
#pragma unroll
        for (int it = 0; it < 4; ++it) {
            const int s = tid + it * 256;
            const int m = s >> 3;
            const int kseg = s & 7;
            float4 v = make_float4(0.f, 0.f, 0.f, 0.f);
            const int mg = bm + m;
            if (mg < NN)
                v = *reinterpret_cast<const float4*>(Ap + (size_t)mg * stride + kk0 + kseg * 8);
            *reinterpret_cast<float4*>(smem + ABASE + m * 128 + ((kseg ^ (m & 7)) << 4)) = v;
        }
        // stage B tile: BN x 64 bf16 (weight rows are B columns)
#pragma unroll
        for (int it = 0; it < B_ITERS; ++it) {
            const int s = tid + it * 256;
            const int f = s >> 3;
            const int kseg = s & 7;
            const float4 v = *reinterpret_cast<const float4*>(
                Wp + (size_t)(bn + f) * stride + kk0 + kseg * 8);
            *reinterpret_cast<float4*>(smem + BBASE + f * 128 + ((kseg ^ (f & 7)) << 4)) = v;
        }
        __syncthreads();

#pragma unroll
        for (int ksub = 0; ksub < 2; ++ksub) {
            const int kb = ksub * 4 + lhi;
            s16x8 a[FM], b[FN];
#pragma unroll
            for (int fm = 0; fm < FM; ++fm)
                a[fm] = *reinterpret_cast<const s16x8*>(
                    smem + ABASE + rowA[fm] * 128 + ((kb ^ (rowA[fm] & 7)) << 4));
#pragma unroll
            for (int fn = 0; fn < FN; ++fn)
                b[fn] = *reinterpret_cast<const s16x8*>(
                    smem + BBASE + rowB[fn] * 128 + ((kb ^ (rowB[fn] & 7)) << 4));
#pragma unroll
            for (int fm = 0; fm < FM; ++fm)
#pragma unroll
                for (int fn = 0; fn < FN; ++fn)
                    acc[fm][fn] = __builtin_amdgcn_mfma_f32_16x16x32_bf16(
                        a[fm], b[fn], acc[fm][fn], 0, 0, 0);
        }
        __syncthreads();
    }

    // epilogue: C/D layout col = l&15, row = (l>>4)*4 + r
#pragma unroll
    for (int fn = 0; fn < FN; ++fn) {
        const int col = bn + wc * WN + fn * 16 + lr;
        const float bv = HASBIAS ? bias[col] : 0.f;
#pragma unroll
        for (int fm = 0; fm < FM; ++fm) {
#pragma unroll
            for (int r = 0; r < 4; ++r) {
                const int row = bm + wr * 64 + fm * 16 + lhi * 4 + r;
                if (row >= NN) continue;
                float v = acc[fm][fn][r] + bv;
                if (HASADD) v += bf2f(addC[(size_t)row * F + col]);
                if (RELU) v = fmaxf(v, 0.f);
                if (OUTBF16)
                    ((unsigned short*)outp)[(size_t)row * F + col] = f2bf(v);
                else
                    ((float*)outp)[(size_t)row * F + col] = v;
            }
        }
    }
}

extern "C" void kernel_launch(void* const* d_in, const int* in_sizes, int n_in,
                              void* d_out, int out_size, void* d_ws, size_t ws_size,
                              hipStream_t stream) {
    const float* feats = (const float*)d_in[0];
    const int*   esrc  = (const int*)d_in[1];
    const int*   edst  = (const int*)d_in[2];
    const float* W0s = (const float*)d_in[3];
    const float* W0n = (const float*)d_in[4];
    const float* b0  = (const float*)d_in[5];
    const float* W1s = (const float*)d_in[6];
    const float* W1n = (const float*)d_in[7];
    const float* b1  = (const float*)d_in[8];
    const float* W2s = (const float*)d_in[9];
    const float* W2n = (const float*)d_in[10];
    const float* b2  = (const float*)d_in[11];
    float* out = (float*)d_out;

    char* p = (char*)d_ws;
    auto alloc = [&](size_t bytes) { char* r = p; p += (bytes + 255) & ~255ull; return r; };
    int*   degi      = (int*)alloc((size_t)NN * 4);
    int*   row_start = (int*)alloc(((size_t)NN + 1) * 4);
    int*   cursor    = (int*)alloc((size_t)NN * 4);
    int*   csr       = (int*)alloc((size_t)NE * 4);
    float* rdeg      = (float*)alloc((size_t)NN * 4);
    unsigned short* wbuf = (unsigned short*)alloc((size_t)229376 * 2);
    unsigned short* fx   = (unsigned short*)alloc((size_t)NN * 128 * 2);
    unsigned short* agg  = (unsigned short*)alloc((size_t)NN * 256 * 2);
    unsigned short* h1   = (unsigned short*)alloc((size_t)NN * 256 * 2);
    unsigned short* h2   = (unsigned short*)alloc((size_t)NN * 256 * 2);
    unsigned short* z    = agg;                    // layer-2 z (N,64)
    unsigned short* aggz = agg + (size_t)NN * 64;  // layer-2 aggregated z (N,64)

    const unsigned short* w0s = wbuf;
    const unsigned short* w0n = wbuf + 32768;
    const unsigned short* w1s = wbuf + 65536;
    const unsigned short* w1n = wbuf + 131072;
    const unsigned short* w2s = wbuf + 196608;
    const unsigned short* w2n = wbuf + 212992;

    // ---- CSR build
    hipMemsetAsync(degi, 0, (size_t)NN * 4, stream);
    deg_hist_kernel<<<(NE + 255) / 256, 256, 0, stream>>>(edst, degi, NE);
    scan_kernel<<<1, 256, 0, stream>>>(degi, row_start, cursor, rdeg);
    fill_csr_kernel<<<(NE + 255) / 256, 256, 0, stream>>>(esrc, edst, cursor, csr, NE);

    // ---- converts
    cvt_f32_bf16<<<(NN * 128 / 4 + 255) / 256, 256, 0, stream>>>(feats, fx, NN * 128 / 4);
    cvt_weights<<<(229376 / 4 + 255) / 256, 256, 0, stream>>>(W0s, W0n, W1s, W1n, W2s, W2n, wbuf);

    const int gather_grid = (NN + 3) / 4;
    const dim3 g256((NN + 127) / 128, 2);
    const dim3 g64((NN + 127) / 128, 1);

    // ---- layer 0: fx[N,128] -> h1[N,256], ReLU
    gather_mean_bf16<128><<<gather_grid, 256, 0, stream>>>(fx, row_start, csr, rdeg, agg);
    mfma_gemm<128, 128, 256, 128, true, true, false, true>
        <<<g256, 256, 0, stream>>>(fx, agg, w0s, w0n, b0, nullptr, h1);

    // ---- layer 1: h1[N,256] -> h2[N,256], ReLU
    gather_mean_bf16<256><<<gather_grid, 256, 0, stream>>>(h1, row_start, csr, rdeg, agg);
    mfma_gemm<256, 256, 256, 128, true, true, false, true>
        <<<g256, 256, 0, stream>>>(h1, agg, w1s, w1n, b1, nullptr, h2);

    // ---- layer 2: transform-before-aggregate
    // z = h2 @ W2n.T (N,64), no bias
    mfma_gemm<256, 0, 64, 64, false, false, false, true>
        <<<g64, 256, 0, stream>>>(h2, nullptr, w2n, nullptr, nullptr, nullptr, z);
    gather_mean_bf16<64><<<gather_grid, 256, 0, stream>>>(z, row_start, csr, rdeg, aggz);
    // out = h2 @ W2s.T + b2 + aggz   (fp32 out)
    mfma_gemm<256, 0, 64, 64, false, true, true, false>
        <<<g64, 256, 0, stream>>>(h2, nullptr, w2s, nullptr, b2, aggz, out);
}

// Round 5
// 697.520 us; speedup vs baseline: 20.7007x; 1.4329x over previous
//
#include <hip/hip_runtime.h>

// GraphSAGE 3-layer. Round 4 (resubmit — prior bench hit GPUAcquisitionTimeout):
// parallel hierarchical prefix scan (was 287us single-block serial scan = 29%
// of total), gather edge-loop unroll 8.
//   - CSR gather aggregation; bf16 activations; MFMA bf16 GEMMs (round-3)
//   - layer 2 transform-before-aggregate (64-wide gather)

constexpr int NN = 100000;
constexpr int NE = 1600000;

typedef short s16x8 __attribute__((ext_vector_type(8)));
typedef float f32x4 __attribute__((ext_vector_type(4)));

struct ushort4_t { unsigned short x, y, z, w; };
struct ushort2_t { unsigned short x, y; };

__device__ __forceinline__ float bf2f(unsigned short u) {
    union { unsigned int i; float f; } c; c.i = ((unsigned int)u) << 16; return c.f;
}
__device__ __forceinline__ unsigned short f2bf(float f) {
    union { float f; unsigned int i; } c; c.f = f;
    unsigned int r = (c.i + 0x7fffu + ((c.i >> 16) & 1u)) >> 16;
    return (unsigned short)r;
}

// ---------------- CSR build ----------------
__global__ void deg_hist_kernel(const int* __restrict__ dst, int* __restrict__ degi, int n) {
    int e = blockIdx.x * blockDim.x + threadIdx.x;
    if (e < n) atomicAdd(&degi[dst[e]], 1);
}

// hierarchical scan: 1024-element chunks
constexpr int SCHUNK = 1024;
constexpr int NCH = (NN + SCHUNK - 1) / SCHUNK;   // 98

__global__ void chunk_sum_kernel(const int* __restrict__ degi, int* __restrict__ csum) {
    __shared__ int red[256];
    const int blk = blockIdx.x, t = threadIdx.x;
    const int base = blk * SCHUNK + t * 4;
    int s = 0;
#pragma unroll
    for (int u = 0; u < 4; ++u) { const int i = base + u; if (i < NN) s += degi[i]; }
    red[t] = s;
    __syncthreads();
    for (int o = 128; o > 0; o >>= 1) {
        if (t < o) red[t] += red[t + o];
        __syncthreads();
    }
    if (t == 0) csum[blk] = red[0];
}

__global__ void chunk_scan_kernel(const int* __restrict__ csum, int* __restrict__ coff,
                                  int* __restrict__ row_start) {
    __shared__ int sh[128];
    const int t = threadIdx.x;
    const int v0 = (t < NCH) ? csum[t] : 0;
    sh[t] = v0;
    __syncthreads();
    for (int o = 1; o < 128; o <<= 1) {
        const int v = (t >= o) ? sh[t - o] : 0;
        __syncthreads();
        sh[t] += v;
        __syncthreads();
    }
    if (t < NCH) coff[t] = sh[t] - v0;   // exclusive
    if (t == 0) row_start[NN] = NE;
}

__global__ void scan_write_kernel(const int* __restrict__ degi, const int* __restrict__ coff,
                                  int* __restrict__ row_start, int* __restrict__ cursor,
                                  float* __restrict__ rdeg) {
    __shared__ int sh[256];
    const int blk = blockIdx.x, t = threadIdx.x;
    const int base = blk * SCHUNK + t * 4;
    int d[4]; int s = 0;
#pragma unroll
    for (int u = 0; u < 4; ++u) { const int i = base + u; d[u] = (i < NN) ? degi[i] : 0; s += d[u]; }
    sh[t] = s;
    __syncthreads();
    for (int o = 1; o < 256; o <<= 1) {
        const int v = (t >= o) ? sh[t - o] : 0;
        __syncthreads();
        sh[t] += v;
        __syncthreads();
    }
    int run = coff[blk] + sh[t] - s;     // exclusive across threads
#pragma unroll
    for (int u = 0; u < 4; ++u) {
        const int i = base + u;
        if (i < NN) {
            row_start[i] = run;
            cursor[i] = run;
            rdeg[i] = 1.0f / (float)max(d[u], 1);
            run += d[u];
        }
    }
}

__global__ void fill_csr_kernel(const int* __restrict__ src, const int* __restrict__ dst,
                                int* __restrict__ cursor, int* __restrict__ csr, int n) {
    int e = blockIdx.x * blockDim.x + threadIdx.x;
    if (e < n) {
        const int p = atomicAdd(&cursor[dst[e]], 1);
        csr[p] = src[e];
    }
}

// ---------------- fp32 -> bf16 converts ----------------
__global__ void cvt_f32_bf16(const float* __restrict__ src, unsigned short* __restrict__ dst, int nquad) {
    int i = blockIdx.x * blockDim.x + threadIdx.x;
    if (i >= nquad) return;
    const float4 v = reinterpret_cast<const float4*>(src)[i];
    ushort4_t o = { f2bf(v.x), f2bf(v.y), f2bf(v.z), f2bf(v.w) };
    reinterpret_cast<ushort4_t*>(dst)[i] = o;
}

__global__ void cvt_weights(const float* a, const float* b, const float* c,
                            const float* d, const float* e, const float* f,
                            unsigned short* __restrict__ o) {
    int i = blockIdx.x * blockDim.x + threadIdx.x;   // quad index
    int q = i * 4;
    if (q >= 229376) return;
    const float* s; int off;
    if      (q <  32768) { s = a; off = 0; }
    else if (q <  65536) { s = b; off = 32768; }
    else if (q < 131072) { s = c; off = 65536; }
    else if (q < 196608) { s = d; off = 131072; }
    else if (q < 212992) { s = e; off = 196608; }
    else                 { s = f; off = 212992; }
    const float4 v = *reinterpret_cast<const float4*>(s + (q - off));
    ushort4_t ov = { f2bf(v.x), f2bf(v.y), f2bf(v.z), f2bf(v.w) };
    *reinterpret_cast<ushort4_t*>(o + q) = ov;
}

// ---------------- gather-mean (bf16 rows, fp32 accum, bf16 out) ----------------
template<int D>
__global__ __launch_bounds__(256) void gather_mean_bf16(
    const unsigned short* __restrict__ rows, const int* __restrict__ row_start,
    const int* __restrict__ csr, const float* __restrict__ rdeg,
    unsigned short* __restrict__ out) {
    constexpr int VPL = D / 64;
    const int node = (int)((blockIdx.x * (unsigned)blockDim.x + threadIdx.x) >> 6);
    if (node >= NN) return;
    const int lane = threadIdx.x & 63;
    const int beg = row_start[node];
    const int end = row_start[node + 1];
    float acc[VPL];
#pragma unroll
    for (int u = 0; u < VPL; ++u) acc[u] = 0.f;

    auto accum = [&](int s) {
        const unsigned short* p = rows + (size_t)s * D + lane * VPL;
        if constexpr (VPL == 4) {
            const ushort4_t v = *reinterpret_cast<const ushort4_t*>(p);
            acc[0] += bf2f(v.x); acc[1] += bf2f(v.y); acc[2] += bf2f(v.z); acc[3] += bf2f(v.w);
        } else if constexpr (VPL == 2) {
            const ushort2_t v = *reinterpret_cast<const ushort2_t*>(p);
            acc[0] += bf2f(v.x); acc[1] += bf2f(v.y);
        } else {
            acc[0] += bf2f(*p);
        }
    };

    int e = beg;
    for (; e + 8 <= end; e += 8) {
        const int s0 = csr[e],     s1 = csr[e + 1], s2 = csr[e + 2], s3 = csr[e + 3];
        const int s4 = csr[e + 4], s5 = csr[e + 5], s6 = csr[e + 6], s7 = csr[e + 7];
        accum(s0); accum(s1); accum(s2); accum(s3);
        accum(s4); accum(s5); accum(s6); accum(s7);
    }
    for (; e + 4 <= end; e += 4) {
        const int s0 = csr[e], s1 = csr[e + 1], s2 = csr[e + 2], s3 = csr[e + 3];
        accum(s0); accum(s1); accum(s2); accum(s3);
    }
    for (; e < end; ++e) accum(csr[e]);

    const float r = rdeg[node];
    unsigned short* o = out + (size_t)node * D + lane * VPL;
    if constexpr (VPL == 4) {
        ushort4_t v = { f2bf(acc[0] * r), f2bf(acc[1] * r), f2bf(acc[2] * r), f2bf(acc[3] * r) };
        *reinterpret_cast<ushort4_t*>(o) = v;
    } else if constexpr (VPL == 2) {
        ushort2_t v = { f2bf(acc[0] * r), f2bf(acc[1] * r) };
        *reinterpret_cast<ushort2_t*>(o) = v;
    } else {
        *o = f2bf(acc[0] * r);
    }
}

// ---------------- MFMA GEMM ----------------
// out[m][f] = sum_k A[m][k]*W[f][k] (+bias[f]) (+addC[m][f]) ; optional ReLU
// A = [A1 | A2] along K (K1 + K2, both multiples of 64). W likewise [W1 ; W2].
// Tile: BM=128 x BN (128 or 64), BK=64, 256 threads = 4 waves (2x2 wave grid).
// LDS layout: [row][BK] bf16, XOR-swizzled: byte ^= (row&7)<<4.
template<int K1, int K2, int F, int BN, bool RELU, bool HASBIAS, bool HASADD, bool OUTBF16>
__global__ __launch_bounds__(256, 2) void mfma_gemm(
    const unsigned short* A1, const unsigned short* A2,
    const unsigned short* __restrict__ W1, const unsigned short* __restrict__ W2,
    const float* __restrict__ bias, const unsigned short* __restrict__ addC,
    void* outp) {

    constexpr int BM = 128, BK = 64;
    constexpr int KA = K1 + K2;
    constexpr int WN = BN / 2;          // wave col extent (64 or 32)
    constexpr int FM = 4, FN = WN / 16;
    constexpr int ABASE = 0;
    constexpr int BBASE = BM * BK * 2;  // 16384
    constexpr int B_ITERS = (BN * 8) / 256;

    __shared__ __align__(16) char smem[(BM + BN) * BK * 2];

    const int tid = threadIdx.x;
    const int l = tid & 63;
    const int w = tid >> 6;
    const int wr = w >> 1, wc = w & 1;
    const int lr = l & 15, lhi = l >> 4;
    const int bm = blockIdx.x * BM;
    const int bn = blockIdx.y * BN;

    f32x4 acc[FM][FN];
#pragma unroll
    for (int i = 0; i < FM; ++i)
#pragma unroll
        for (int j = 0; j < FN; ++j) acc[i][j] = (f32x4){0.f, 0.f, 0.f, 0.f};

    int rowA[FM], rowB[FN];
#pragma unroll
    for (int fm = 0; fm < FM; ++fm) rowA[fm] = wr * 64 + fm * 16 + lr;
#pragma unroll
    for (int fn = 0; fn < FN; ++fn) rowB[fn] = wc * WN + fn * 16 + lr;

    for (int k0 = 0; k0 < KA; k0 += BK) {
        const bool inR1 = (k0 < K1);
        const unsigned short* Ap = inR1 ? A1 : A2;
        const unsigned short* Wp = inR1 ? W1 : W2;
        const int stride = inR1 ? K1 : K2;
        const int kk0 = inR1 ? k0 : (k0 - K1);

        // stage A tile: 128 x 64 bf16, 16B per thread-iter
#pragma unroll
        for (int it = 0; it < 4; ++it) {
            const int s = tid + it * 256;
            const int m = s >> 3;
            const int kseg = s & 7;
            float4 v = make_float4(0.f, 0.f, 0.f, 0.f);
            const int mg = bm + m;
            if (mg < NN)
                v = *reinterpret_cast<const float4*>(Ap + (size_t)mg * stride + kk0 + kseg * 8);
            *reinterpret_cast<float4*>(smem + ABASE + m * 128 + ((kseg ^ (m & 7)) << 4)) = v;
        }
        // stage B tile: BN x 64 bf16 (weight rows are B columns)
#pragma unroll
        for (int it = 0; it < B_ITERS; ++it) {
            const int s = tid + it * 256;
            const int f = s >> 3;
            const int kseg = s & 7;
            const float4 v = *reinterpret_cast<const float4*>(
                Wp + (size_t)(bn + f) * stride + kk0 + kseg * 8);
            *reinterpret_cast<float4*>(smem + BBASE + f * 128 + ((kseg ^ (f & 7)) << 4)) = v;
        }
        __syncthreads();

#pragma unroll
        for (int ksub = 0; ksub < 2; ++ksub) {
            const int kb = ksub * 4 + lhi;
            s16x8 a[FM], b[FN];
#pragma unroll
            for (int fm = 0; fm < FM; ++fm)
                a[fm] = *reinterpret_cast<const s16x8*>(
                    smem + ABASE + rowA[fm] * 128 + ((kb ^ (rowA[fm] & 7)) << 4));
#pragma unroll
            for (int fn = 0; fn < FN; ++fn)
                b[fn] = *reinterpret_cast<const s16x8*>(
                    smem + BBASE + rowB[fn] * 128 + ((kb ^ (rowB[fn] & 7)) << 4));
#pragma unroll
            for (int fm = 0; fm < FM; ++fm)
#pragma unroll
                for (int fn = 0; fn < FN; ++fn)
                    acc[fm][fn] = __builtin_amdgcn_mfma_f32_16x16x32_bf16(
                        a[fm], b[fn], acc[fm][fn], 0, 0, 0);
        }
        __syncthreads();
    }

    // epilogue: C/D layout col = l&15, row = (l>>4)*4 + r
#pragma unroll
    for (int fn = 0; fn < FN; ++fn) {
        const int col = bn + wc * WN + fn * 16 + lr;
        const float bv = HASBIAS ? bias[col] : 0.f;
#pragma unroll
        for (int fm = 0; fm < FM; ++fm) {
#pragma unroll
            for (int r = 0; r < 4; ++r) {
                const int row = bm + wr * 64 + fm * 16 + lhi * 4 + r;
                if (row >= NN) continue;
                float v = acc[fm][fn][r] + bv;
                if (HASADD) v += bf2f(addC[(size_t)row * F + col]);
                if (RELU) v = fmaxf(v, 0.f);
                if (OUTBF16)
                    ((unsigned short*)outp)[(size_t)row * F + col] = f2bf(v);
                else
                    ((float*)outp)[(size_t)row * F + col] = v;
            }
        }
    }
}

extern "C" void kernel_launch(void* const* d_in, const int* in_sizes, int n_in,
                              void* d_out, int out_size, void* d_ws, size_t ws_size,
                              hipStream_t stream) {
    const float* feats = (const float*)d_in[0];
    const int*   esrc  = (const int*)d_in[1];
    const int*   edst  = (const int*)d_in[2];
    const float* W0s = (const float*)d_in[3];
    const float* W0n = (const float*)d_in[4];
    const float* b0  = (const float*)d_in[5];
    const float* W1s = (const float*)d_in[6];
    const float* W1n = (const float*)d_in[7];
    const float* b1  = (const float*)d_in[8];
    const float* W2s = (const float*)d_in[9];
    const float* W2n = (const float*)d_in[10];
    const float* b2  = (const float*)d_in[11];
    float* out = (float*)d_out;

    char* p = (char*)d_ws;
    auto alloc = [&](size_t bytes) { char* r = p; p += (bytes + 255) & ~255ull; return r; };
    int*   degi      = (int*)alloc((size_t)NN * 4);
    int*   row_start = (int*)alloc(((size_t)NN + 1) * 4);
    int*   cursor    = (int*)alloc((size_t)NN * 4);
    int*   csr       = (int*)alloc((size_t)NE * 4);
    float* rdeg      = (float*)alloc((size_t)NN * 4);
    int*   csum      = (int*)alloc((size_t)NCH * 4);
    int*   coff      = (int*)alloc((size_t)NCH * 4);
    unsigned short* wbuf = (unsigned short*)alloc((size_t)229376 * 2);
    unsigned short* fx   = (unsigned short*)alloc((size_t)NN * 128 * 2);
    unsigned short* agg  = (unsigned short*)alloc((size_t)NN * 256 * 2);
    unsigned short* h1   = (unsigned short*)alloc((size_t)NN * 256 * 2);
    unsigned short* h2   = (unsigned short*)alloc((size_t)NN * 256 * 2);
    unsigned short* z    = agg;                    // layer-2 z (N,64)
    unsigned short* aggz = agg + (size_t)NN * 64;  // layer-2 aggregated z (N,64)

    const unsigned short* w0s = wbuf;
    const unsigned short* w0n = wbuf + 32768;
    const unsigned short* w1s = wbuf + 65536;
    const unsigned short* w1n = wbuf + 131072;
    const unsigned short* w2s = wbuf + 196608;
    const unsigned short* w2n = wbuf + 212992;

    // ---- CSR build (parallel scan)
    hipMemsetAsync(degi, 0, (size_t)NN * 4, stream);
    deg_hist_kernel<<<(NE + 255) / 256, 256, 0, stream>>>(edst, degi, NE);
    chunk_sum_kernel<<<NCH, 256, 0, stream>>>(degi, csum);
    chunk_scan_kernel<<<1, 128, 0, stream>>>(csum, coff, row_start);
    scan_write_kernel<<<NCH, 256, 0, stream>>>(degi, coff, row_start, cursor, rdeg);
    fill_csr_kernel<<<(NE + 255) / 256, 256, 0, stream>>>(esrc, edst, cursor, csr, NE);

    // ---- converts
    cvt_f32_bf16<<<(NN * 128 / 4 + 255) / 256, 256, 0, stream>>>(feats, fx, NN * 128 / 4);
    cvt_weights<<<(229376 / 4 + 255) / 256, 256, 0, stream>>>(W0s, W0n, W1s, W1n, W2s, W2n, wbuf);

    const int gather_grid = (NN + 3) / 4;
    const dim3 g256((NN + 127) / 128, 2);
    const dim3 g64((NN + 127) / 128, 1);

    // ---- layer 0: fx[N,128] -> h1[N,256], ReLU
    gather_mean_bf16<128><<<gather_grid, 256, 0, stream>>>(fx, row_start, csr, rdeg, agg);
    mfma_gemm<128, 128, 256, 128, true, true, false, true>
        <<<g256, 256, 0, stream>>>(fx, agg, w0s, w0n, b0, nullptr, h1);

    // ---- layer 1: h1[N,256] -> h2[N,256], ReLU
    gather_mean_bf16<256><<<gather_grid, 256, 0, stream>>>(h1, row_start, csr, rdeg, agg);
    mfma_gemm<256, 256, 256, 128, true, true, false, true>
        <<<g256, 256, 0, stream>>>(h1, agg, w1s, w1n, b1, nullptr, h2);

    // ---- layer 2: transform-before-aggregate
    // z = h2 @ W2n.T (N,64), no bias
    mfma_gemm<256, 0, 64, 64, false, false, false, true>
        <<<g64, 256, 0, stream>>>(h2, nullptr, w2n, nullptr, nullptr, nullptr, z);
    gather_mean_bf16<64><<<gather_grid, 256, 0, stream>>>(z, row_start, csr, rdeg, aggz);
    // out = h2 @ W2s.T + b2 + aggz   (fp32 out)
    mfma_gemm<256, 0, 64, 64, false, true, true, false>
        <<<g64, 256, 0, stream>>>(h2, nullptr, w2s, nullptr, b2, aggz, out);
}

// Round 6
// 618.971 us; speedup vs baseline: 23.3277x; 1.1269x over previous
//
#include <hip/hip_runtime.h>

// GraphSAGE 3-layer. Round 6: two-phase bucketed CSR fill.
//   fill_csr was 127us with WRITE_SIZE=105MB for a 6.4MB array (random 4B
//   scatter -> every 64B line written ~17x). Phase A buckets edges by dst>>8
//   (LDS histogram + bulk-reserved contiguous ebuf ranges, bases from
//   row_start[b*256]); Phase B scatters within a 16KB L2-resident window with
//   LDS cursors (global cursor array deleted).
//   - CSR gather aggregation; bf16 activations; MFMA bf16 GEMMs
//   - layer 2 transform-before-aggregate (64-wide gather)

constexpr int NN = 100000;
constexpr int NE = 1600000;

typedef short s16x8 __attribute__((ext_vector_type(8)));
typedef float f32x4 __attribute__((ext_vector_type(4)));

struct ushort4_t { unsigned short x, y, z, w; };
struct ushort2_t { unsigned short x, y; };

__device__ __forceinline__ float bf2f(unsigned short u) {
    union { unsigned int i; float f; } c; c.i = ((unsigned int)u) << 16; return c.f;
}
__device__ __forceinline__ unsigned short f2bf(float f) {
    union { float f; unsigned int i; } c; c.f = f;
    unsigned int r = (c.i + 0x7fffu + ((c.i >> 16) & 1u)) >> 16;
    return (unsigned short)r;
}

// ---------------- CSR build ----------------
__global__ void deg_hist_kernel(const int* __restrict__ dst, int* __restrict__ degi, int n) {
    int e = blockIdx.x * blockDim.x + threadIdx.x;
    if (e < n) atomicAdd(&degi[dst[e]], 1);
}

// hierarchical scan: 1024-element chunks
constexpr int SCHUNK = 1024;
constexpr int NCH = (NN + SCHUNK - 1) / SCHUNK;   // 98
// dst buckets for CSR fill: 256 nodes each
constexpr int NB = (NN + 255) / 256;              // 391

__global__ void chunk_sum_kernel(const int* __restrict__ degi, int* __restrict__ csum) {
    __shared__ int red[256];
    const int blk = blockIdx.x, t = threadIdx.x;
    const int base = blk * SCHUNK + t * 4;
    int s = 0;
#pragma unroll
    for (int u = 0; u < 4; ++u) { const int i = base + u; if (i < NN) s += degi[i]; }
    red[t] = s;
    __syncthreads();
    for (int o = 128; o > 0; o >>= 1) {
        if (t < o) red[t] += red[t + o];
        __syncthreads();
    }
    if (t == 0) csum[blk] = red[0];
}

__global__ void chunk_scan_kernel(const int* __restrict__ csum, int* __restrict__ coff,
                                  int* __restrict__ row_start) {
    __shared__ int sh[128];
    const int t = threadIdx.x;
    const int v0 = (t < NCH) ? csum[t] : 0;
    sh[t] = v0;
    __syncthreads();
    for (int o = 1; o < 128; o <<= 1) {
        const int v = (t >= o) ? sh[t - o] : 0;
        __syncthreads();
        sh[t] += v;
        __syncthreads();
    }
    if (t < NCH) coff[t] = sh[t] - v0;   // exclusive
    if (t == 0) row_start[NN] = NE;
}

// writes row_start, rdeg, and per-bucket ebuf cursors (gcur[b] = row_start[b*256])
__global__ void scan_write_kernel(const int* __restrict__ degi, const int* __restrict__ coff,
                                  int* __restrict__ row_start, int* __restrict__ gcur,
                                  float* __restrict__ rdeg) {
    __shared__ int sh[256];
    const int blk = blockIdx.x, t = threadIdx.x;
    const int base = blk * SCHUNK + t * 4;
    int d[4]; int s = 0;
#pragma unroll
    for (int u = 0; u < 4; ++u) { const int i = base + u; d[u] = (i < NN) ? degi[i] : 0; s += d[u]; }
    sh[t] = s;
    __syncthreads();
    for (int o = 1; o < 256; o <<= 1) {
        const int v = (t >= o) ? sh[t - o] : 0;
        __syncthreads();
        sh[t] += v;
        __syncthreads();
    }
    int run = coff[blk] + sh[t] - s;     // exclusive across threads
#pragma unroll
    for (int u = 0; u < 4; ++u) {
        const int i = base + u;
        if (i < NN) {
            row_start[i] = run;
            if ((i & 255) == 0) gcur[i >> 8] = run;
            rdeg[i] = 1.0f / (float)max(d[u], 1);
            run += d[u];
        }
    }
}

// Phase A: bucket edges (src,dst) into contiguous per-bucket ranges of ebuf.
constexpr int EPB_A = 4096;   // edges per block
__global__ __launch_bounds__(256) void bucket_scatter_kernel(
    const int* __restrict__ src, const int* __restrict__ dst,
    int* __restrict__ gcur, int2* __restrict__ ebuf) {
    __shared__ int hist[NB];
    __shared__ int base[NB];
    const int blk = blockIdx.x, t = threadIdx.x;
    int myS[16], myD[16];
#pragma unroll
    for (int u = 0; u < 16; ++u) {
        const int i = blk * EPB_A + u * 256 + t;
        if (i < NE) { myS[u] = src[i]; myD[u] = dst[i]; } else myD[u] = -1;
    }
    for (int b = t; b < NB; b += 256) hist[b] = 0;
    __syncthreads();
#pragma unroll
    for (int u = 0; u < 16; ++u)
        if (myD[u] >= 0) atomicAdd(&hist[myD[u] >> 8], 1);
    __syncthreads();
    for (int b = t; b < NB; b += 256) {
        const int c = hist[b];
        base[b] = c ? atomicAdd(&gcur[b], c) : 0;
    }
    __syncthreads();
    for (int b = t; b < NB; b += 256) hist[b] = 0;
    __syncthreads();
#pragma unroll
    for (int u = 0; u < 16; ++u)
        if (myD[u] >= 0) {
            const int bk = myD[u] >> 8;
            const int off = atomicAdd(&hist[bk], 1);
            ebuf[base[bk] + off] = make_int2(myS[u], myD[u]);
        }
}

// Phase B: one block per bucket; LDS cursors; scatter into 16KB csr window.
__global__ __launch_bounds__(256) void bucket_fill_kernel(
    const int2* __restrict__ ebuf, const int* __restrict__ row_start,
    int* __restrict__ csr) {
    __shared__ int lcur[256];
    const int b = blockIdx.x, t = threadIdx.x;
    const int nbase = b << 8;
    const int nend = min(nbase + 256, NN);
    if (nbase + t < nend) lcur[t] = row_start[nbase + t];
    __syncthreads();
    const int beg = row_start[nbase];
    const int end = row_start[nend];   // row_start[NN] = NE for last bucket
    for (int i = beg + t; i < end; i += 256) {
        const int2 e = ebuf[i];
        const int p = atomicAdd(&lcur[e.y & 255], 1);
        csr[p] = e.x;
    }
}

// ---------------- fp32 -> bf16 converts ----------------
__global__ void cvt_f32_bf16(const float* __restrict__ src, unsigned short* __restrict__ dst, int nquad) {
    int i = blockIdx.x * blockDim.x + threadIdx.x;
    if (i >= nquad) return;
    const float4 v = reinterpret_cast<const float4*>(src)[i];
    ushort4_t o = { f2bf(v.x), f2bf(v.y), f2bf(v.z), f2bf(v.w) };
    reinterpret_cast<ushort4_t*>(dst)[i] = o;
}

__global__ void cvt_weights(const float* a, const float* b, const float* c,
                            const float* d, const float* e, const float* f,
                            unsigned short* __restrict__ o) {
    int i = blockIdx.x * blockDim.x + threadIdx.x;   // quad index
    int q = i * 4;
    if (q >= 229376) return;
    const float* s; int off;
    if      (q <  32768) { s = a; off = 0; }
    else if (q <  65536) { s = b; off = 32768; }
    else if (q < 131072) { s = c; off = 65536; }
    else if (q < 196608) { s = d; off = 131072; }
    else if (q < 212992) { s = e; off = 196608; }
    else                 { s = f; off = 212992; }
    const float4 v = *reinterpret_cast<const float4*>(s + (q - off));
    ushort4_t ov = { f2bf(v.x), f2bf(v.y), f2bf(v.z), f2bf(v.w) };
    *reinterpret_cast<ushort4_t*>(o + q) = ov;
}

// ---------------- gather-mean (bf16 rows, fp32 accum, bf16 out) ----------------
template<int D>
__global__ __launch_bounds__(256) void gather_mean_bf16(
    const unsigned short* __restrict__ rows, const int* __restrict__ row_start,
    const int* __restrict__ csr, const float* __restrict__ rdeg,
    unsigned short* __restrict__ out) {
    constexpr int VPL = D / 64;
    const int node = (int)((blockIdx.x * (unsigned)blockDim.x + threadIdx.x) >> 6);
    if (node >= NN) return;
    const int lane = threadIdx.x & 63;
    const int beg = row_start[node];
    const int end = row_start[node + 1];
    float acc[VPL];
#pragma unroll
    for (int u = 0; u < VPL; ++u) acc[u] = 0.f;

    auto accum = [&](int s) {
        const unsigned short* p = rows + (size_t)s * D + lane * VPL;
        if constexpr (VPL == 4) {
            const ushort4_t v = *reinterpret_cast<const ushort4_t*>(p);
            acc[0] += bf2f(v.x); acc[1] += bf2f(v.y); acc[2] += bf2f(v.z); acc[3] += bf2f(v.w);
        } else if constexpr (VPL == 2) {
            const ushort2_t v = *reinterpret_cast<const ushort2_t*>(p);
            acc[0] += bf2f(v.x); acc[1] += bf2f(v.y);
        } else {
            acc[0] += bf2f(*p);
        }
    };

    int e = beg;
    for (; e + 8 <= end; e += 8) {
        const int s0 = csr[e],     s1 = csr[e + 1], s2 = csr[e + 2], s3 = csr[e + 3];
        const int s4 = csr[e + 4], s5 = csr[e + 5], s6 = csr[e + 6], s7 = csr[e + 7];
        accum(s0); accum(s1); accum(s2); accum(s3);
        accum(s4); accum(s5); accum(s6); accum(s7);
    }
    for (; e + 4 <= end; e += 4) {
        const int s0 = csr[e], s1 = csr[e + 1], s2 = csr[e + 2], s3 = csr[e + 3];
        accum(s0); accum(s1); accum(s2); accum(s3);
    }
    for (; e < end; ++e) accum(csr[e]);

    const float r = rdeg[node];
    unsigned short* o = out + (size_t)node * D + lane * VPL;
    if constexpr (VPL == 4) {
        ushort4_t v = { f2bf(acc[0] * r), f2bf(acc[1] * r), f2bf(acc[2] * r), f2bf(acc[3] * r) };
        *reinterpret_cast<ushort4_t*>(o) = v;
    } else if constexpr (VPL == 2) {
        ushort2_t v = { f2bf(acc[0] * r), f2bf(acc[1] * r) };
        *reinterpret_cast<ushort2_t*>(o) = v;
    } else {
        *o = f2bf(acc[0] * r);
    }
}

// ---------------- MFMA GEMM ----------------
// out[m][f] = sum_k A[m][k]*W[f][k] (+bias[f]) (+addC[m][f]) ; optional ReLU
// A = [A1 | A2] along K (K1 + K2, both multiples of 64). W likewise [W1 ; W2].
// Tile: BM=128 x BN (128 or 64), BK=64, 256 threads = 4 waves (2x2 wave grid).
// LDS layout: [row][BK] bf16, XOR-swizzled: byte ^= (row&7)<<4.
template<int K1, int K2, int F, int BN, bool RELU, bool HASBIAS, bool HASADD, bool OUTBF16>
__global__ __launch_bounds__(256, 2) void mfma_gemm(
    const unsigned short* A1, const unsigned short* A2,
    const unsigned short* __restrict__ W1, const unsigned short* __restrict__ W2,
    const float* __restrict__ bias, const unsigned short* __restrict__ addC,
    void* outp) {

    constexpr int BM = 128, BK = 64;
    constexpr int KA = K1 + K2;
    constexpr int WN = BN / 2;          // wave col extent (64 or 32)
    constexpr int FM = 4, FN = WN / 16;
    constexpr int ABASE = 0;
    constexpr int BBASE = BM * BK * 2;  // 16384
    constexpr int B_ITERS = (BN * 8) / 256;

    __shared__ __align__(16) char smem[(BM + BN) * BK * 2];

    const int tid = threadIdx.x;
    const int l = tid & 63;
    const int w = tid >> 6;
    const int wr = w >> 1, wc = w & 1;
    const int lr = l & 15, lhi = l >> 4;
    const int bm = blockIdx.x * BM;
    const int bn = blockIdx.y * BN;

    f32x4 acc[FM][FN];
#pragma unroll
    for (int i = 0; i < FM; ++i)
#pragma unroll
        for (int j = 0; j < FN; ++j) acc[i][j] = (f32x4){0.f, 0.f, 0.f, 0.f};

    int rowA[FM], rowB[FN];
#pragma unroll
    for (int fm = 0; fm < FM; ++fm) rowA[fm] = wr * 64 + fm * 16 + lr;
#pragma unroll
    for (int fn = 0; fn < FN; ++fn) rowB[fn] = wc * WN + fn * 16 + lr;

    for (int k0 = 0; k0 < KA; k0 += BK) {
        const bool inR1 = (k0 < K1);
        const unsigned short* Ap = inR1 ? A1 : A2;
        const unsigned short* Wp = inR1 ? W1 : W2;
        const int stride = inR1 ? K1 : K2;
        const int kk0 = inR1 ? k0 : (k0 - K1);

        // stage A tile: 128 x 64 bf16, 16B per thread-iter
#pragma unroll
        for (int it = 0; it < 4; ++it) {
            const int s = tid + it * 256;
            const int m = s >> 3;
            const int kseg = s & 7;
            float4 v = make_float4(0.f, 0.f, 0.f, 0.f);
            const int mg = bm + m;
            if (mg < NN)
                v = *reinterpret_cast<const float4*>(Ap + (size_t)mg * stride + kk0 + kseg * 8);
            *reinterpret_cast<float4*>(smem + ABASE + m * 128 + ((kseg ^ (m & 7)) << 4)) = v;
        }
        // stage B tile: BN x 64 bf16 (weight rows are B columns)
#pragma unroll
        for (int it = 0; it < B_ITERS; ++it) {
            const int s = tid + it * 256;
            const int f = s >> 3;
            const int kseg = s & 7;
            const float4 v = *reinterpret_cast<const float4*>(
                Wp + (size_t)(bn + f) * stride + kk0 + kseg * 8);
            *reinterpret_cast<float4*>(smem + BBASE + f * 128 + ((kseg ^ (f & 7)) << 4)) = v;
        }
        __syncthreads();

#pragma unroll
        for (int ksub = 0; ksub < 2; ++ksub) {
            const int kb = ksub * 4 + lhi;
            s16x8 a[FM], b[FN];
#pragma unroll
            for (int fm = 0; fm < FM; ++fm)
                a[fm] = *reinterpret_cast<const s16x8*>(
                    smem + ABASE + rowA[fm] * 128 + ((kb ^ (rowA[fm] & 7)) << 4));
#pragma unroll
            for (int fn = 0; fn < FN; ++fn)
                b[fn] = *reinterpret_cast<const s16x8*>(
                    smem + BBASE + rowB[fn] * 128 + ((kb ^ (rowB[fn] & 7)) << 4));
#pragma unroll
            for (int fm = 0; fm < FM; ++fm)
#pragma unroll
                for (int fn = 0; fn < FN; ++fn)
                    acc[fm][fn] = __builtin_amdgcn_mfma_f32_16x16x32_bf16(
                        a[fm], b[fn], acc[fm][fn], 0, 0, 0);
        }
        __syncthreads();
    }

    // epilogue: C/D layout col = l&15, row = (l>>4)*4 + r
#pragma unroll
    for (int fn = 0; fn < FN; ++fn) {
        const int col = bn + wc * WN + fn * 16 + lr;
        const float bv = HASBIAS ? bias[col] : 0.f;
#pragma unroll
        for (int fm = 0; fm < FM; ++fm) {
#pragma unroll
            for (int r = 0; r < 4; ++r) {
                const int row = bm + wr * 64 + fm * 16 + lhi * 4 + r;
                if (row >= NN) continue;
                float v = acc[fm][fn][r] + bv;
                if (HASADD) v += bf2f(addC[(size_t)row * F + col]);
                if (RELU) v = fmaxf(v, 0.f);
                if (OUTBF16)
                    ((unsigned short*)outp)[(size_t)row * F + col] = f2bf(v);
                else
                    ((float*)outp)[(size_t)row * F + col] = v;
            }
        }
    }
}

extern "C" void kernel_launch(void* const* d_in, const int* in_sizes, int n_in,
                              void* d_out, int out_size, void* d_ws, size_t ws_size,
                              hipStream_t stream) {
    const float* feats = (const float*)d_in[0];
    const int*   esrc  = (const int*)d_in[1];
    const int*   edst  = (const int*)d_in[2];
    const float* W0s = (const float*)d_in[3];
    const float* W0n = (const float*)d_in[4];
    const float* b0  = (const float*)d_in[5];
    const float* W1s = (const float*)d_in[6];
    const float* W1n = (const float*)d_in[7];
    const float* b1  = (const float*)d_in[8];
    const float* W2s = (const float*)d_in[9];
    const float* W2n = (const float*)d_in[10];
    const float* b2  = (const float*)d_in[11];
    float* out = (float*)d_out;

    char* p = (char*)d_ws;
    auto alloc = [&](size_t bytes) { char* r = p; p += (bytes + 255) & ~255ull; return r; };
    int*   degi      = (int*)alloc((size_t)NN * 4);
    int*   row_start = (int*)alloc(((size_t)NN + 1) * 4);
    int*   gcur      = (int*)alloc((size_t)NB * 4);
    int*   csr       = (int*)alloc((size_t)NE * 4);
    int2*  ebuf      = (int2*)alloc((size_t)NE * 8);
    float* rdeg      = (float*)alloc((size_t)NN * 4);
    int*   csum      = (int*)alloc((size_t)NCH * 4);
    int*   coff      = (int*)alloc((size_t)NCH * 4);
    unsigned short* wbuf = (unsigned short*)alloc((size_t)229376 * 2);
    unsigned short* fx   = (unsigned short*)alloc((size_t)NN * 128 * 2);
    unsigned short* agg  = (unsigned short*)alloc((size_t)NN * 256 * 2);
    unsigned short* h1   = (unsigned short*)alloc((size_t)NN * 256 * 2);
    unsigned short* h2   = (unsigned short*)alloc((size_t)NN * 256 * 2);
    unsigned short* z    = agg;                    // layer-2 z (N,64)
    unsigned short* aggz = agg + (size_t)NN * 64;  // layer-2 aggregated z (N,64)

    const unsigned short* w0s = wbuf;
    const unsigned short* w0n = wbuf + 32768;
    const unsigned short* w1s = wbuf + 65536;
    const unsigned short* w1n = wbuf + 131072;
    const unsigned short* w2s = wbuf + 196608;
    const unsigned short* w2n = wbuf + 212992;

    // ---- CSR build (parallel scan + two-phase bucketed fill)
    hipMemsetAsync(degi, 0, (size_t)NN * 4, stream);
    deg_hist_kernel<<<(NE + 255) / 256, 256, 0, stream>>>(edst, degi, NE);
    chunk_sum_kernel<<<NCH, 256, 0, stream>>>(degi, csum);
    chunk_scan_kernel<<<1, 128, 0, stream>>>(csum, coff, row_start);
    scan_write_kernel<<<NCH, 256, 0, stream>>>(degi, coff, row_start, gcur, rdeg);
    bucket_scatter_kernel<<<(NE + EPB_A - 1) / EPB_A, 256, 0, stream>>>(esrc, edst, gcur, ebuf);
    bucket_fill_kernel<<<NB, 256, 0, stream>>>(ebuf, row_start, csr);

    // ---- converts
    cvt_f32_bf16<<<(NN * 128 / 4 + 255) / 256, 256, 0, stream>>>(feats, fx, NN * 128 / 4);
    cvt_weights<<<(229376 / 4 + 255) / 256, 256, 0, stream>>>(W0s, W0n, W1s, W1n, W2s, W2n, wbuf);

    const int gather_grid = (NN + 3) / 4;
    const dim3 g256((NN + 127) / 128, 2);
    const dim3 g64((NN + 127) / 128, 1);

    // ---- layer 0: fx[N,128] -> h1[N,256], ReLU
    gather_mean_bf16<128><<<gather_grid, 256, 0, stream>>>(fx, row_start, csr, rdeg, agg);
    mfma_gemm<128, 128, 256, 128, true, true, false, true>
        <<<g256, 256, 0, stream>>>(fx, agg, w0s, w0n, b0, nullptr, h1);

    // ---- layer 1: h1[N,256] -> h2[N,256], ReLU
    gather_mean_bf16<256><<<gather_grid, 256, 0, stream>>>(h1, row_start, csr, rdeg, agg);
    mfma_gemm<256, 256, 256, 128, true, true, false, true>
        <<<g256, 256, 0, stream>>>(h1, agg, w1s, w1n, b1, nullptr, h2);

    // ---- layer 2: transform-before-aggregate
    // z = h2 @ W2n.T (N,64), no bias
    mfma_gemm<256, 0, 64, 64, false, false, false, true>
        <<<g64, 256, 0, stream>>>(h2, nullptr, w2n, nullptr, nullptr, nullptr, z);
    gather_mean_bf16<64><<<gather_grid, 256, 0, stream>>>(z, row_start, csr, rdeg, aggz);
    // out = h2 @ W2s.T + b2 + aggz   (fp32 out)
    mfma_gemm<256, 0, 64, 64, false, true, true, false>
        <<<g64, 256, 0, stream>>>(h2, nullptr, w2s, nullptr, b2, aggz, out);
}